// Round 3
// baseline (262695.142 us; speedup 1.0000x reference)
//
#include <hip/hip_runtime.h>
#include <hip/hip_bf16.h>
#include <hip/hip_cooperative_groups.h>

namespace cg = cooperative_groups;

#define BDIM 128
#define TDIM 1024
#define NIN  512
#define NH   1024
#define NOUT 256
#define KTOT (NIN + NH)          // 1536
#define NITER (TDIM + 2)

__device__ __forceinline__ float sigmoidf_(float x) { return 1.f / (1.f + __expf(-x)); }

struct ScanArgs {
    const float* u;
    const float* Wu[4];      // [512][1024] each
    const float* Wh[4];      // [1024][1024] each
    const float* Wpack;      // [256][1536][16] packed (g-major x 4 cols), or null
    const float* WhyT;       // [256][1024]
    const float* bg[4];
    const float* by;
    float* hb0; float* hb1;  // [128][1024] ping-pong h
    float* lg0; float* lg1;  // [128][256]  ping-pong logits
    float* out;              // [128][1024][256]
};

// ---------------------------------------------------------------------------
// One scan iteration. 256 blocks x 1024 threads (16 waves).
// Gate GEMM: block bx owns h-cols c0..c0+4 for all 4 gates; chunk remap
//   cc=(bx&7)*32+(bx>>3) makes each XCD's 32 blocks cover contiguous 128 cols.
//   Lane: bits0-2 = ks (K-split 8), bits3-4 = gate, bit5 = rg_lo;
//   rg = wave*2+rg_lo (32 groups x 4 rows). K-slice: 64 u-k + 128 h-k.
//   Packed weights: Wpack[cc][k][g*4+j] -> fully-dense 64B lines.
//   Reduce over ks via 3x shfl_xor; ks==0 lanes write LDS; combine -> hnext.
// Y logits (y_{it-1} = h_it @ Why + by): blocks 0..127 = 2 rowgroups x 64
//   colgroups... (bx&1)*64 rows x 4 cols, K-split 4, shfl reduce.
// Softmax (y_{it-2}): blocks 128..255, wave 0, one batch-row each.
// ---------------------------------------------------------------------------
template <bool PACKED>
__device__ __forceinline__ void scan_iter(const ScanArgs& A, int it, float* pre)
{
    const int tid  = threadIdx.x;
    const int bx   = blockIdx.x;
    const int lane = tid & 63;
    const int wv   = tid >> 6;
    const int ks   = lane & 7;
    const int cgi  = (lane >> 3) & 3;
    const int rg   = wv * 2 + (lane >> 5);
    const int cc   = (bx & 7) * 32 + (bx >> 3);   // XCD-contiguous chunk
    const int c0   = cc * 4;

    const float* hcur = (it & 1) ? A.hb1 : A.hb0;
    float* hnext      = (it & 1) ? A.hb0 : A.hb1;
    float* Lw         = (it & 1) ? A.lg1 : A.lg0;
    const float* Lr   = (it & 1) ? A.lg0 : A.lg1;

    // ---------------- softmax of logits from step it-2 (blocks 128..255) ----
    if (it >= 2 && bx >= 128 && tid < 64) {
        const int r = bx - 128, t = it - 2;
        float4 v = *(const float4*)(Lr + (size_t)r * NOUT + tid * 4);
        float mx = fmaxf(fmaxf(v.x, v.y), fmaxf(v.z, v.w));
#pragma unroll
        for (int d = 1; d < 64; d <<= 1) mx = fmaxf(mx, __shfl_xor(mx, d));
        v.x = __expf(v.x - mx); v.y = __expf(v.y - mx);
        v.z = __expf(v.z - mx); v.w = __expf(v.w - mx);
        float s = v.x + v.y + v.z + v.w;
#pragma unroll
        for (int d = 1; d < 64; d <<= 1) s += __shfl_xor(s, d);
        const float inv = 1.f / s;
        v.x *= inv; v.y *= inv; v.z *= inv; v.w *= inv;
        *(float4*)(A.out + ((size_t)r * TDIM + t) * NOUT + tid * 4) = v;
    }

    // ---------------- gate pre-activation GEMM ----------------
    if (it < TDIM) {
        const int t  = it;
        const int r0 = rg * 4;
        float acc[4][4];
#pragma unroll
        for (int i = 0; i < 4; ++i)
#pragma unroll
            for (int j = 0; j < 4; ++j) acc[i][j] = 0.f;

        if (PACKED) {
            const float* pk = A.Wpack + ((size_t)cc * KTOT) * 16 + cgi * 4;
            {   // u-part: k in [ks*64, ks*64+64)
                const float* pku = pk + (size_t)(ks * 64) * 16;
                const float* up  = A.u + (size_t)t * NIN + (size_t)ks * 64;
#pragma unroll 2
                for (int q = 0; q < 16; ++q) {
                    const int k4 = q * 4;
                    const float4 w0 = *(const float4*)(pku + (k4 + 0) * 16);
                    const float4 w1 = *(const float4*)(pku + (k4 + 1) * 16);
                    const float4 w2 = *(const float4*)(pku + (k4 + 2) * 16);
                    const float4 w3 = *(const float4*)(pku + (k4 + 3) * 16);
#pragma unroll
                    for (int i = 0; i < 4; ++i) {
                        const float4 a = *(const float4*)(up +
                            (size_t)(r0 + i) * TDIM * NIN + k4);
                        acc[i][0] = fmaf(a.x, w0.x, acc[i][0]);
                        acc[i][1] = fmaf(a.x, w0.y, acc[i][1]);
                        acc[i][2] = fmaf(a.x, w0.z, acc[i][2]);
                        acc[i][3] = fmaf(a.x, w0.w, acc[i][3]);
                        acc[i][0] = fmaf(a.y, w1.x, acc[i][0]);
                        acc[i][1] = fmaf(a.y, w1.y, acc[i][1]);
                        acc[i][2] = fmaf(a.y, w1.z, acc[i][2]);
                        acc[i][3] = fmaf(a.y, w1.w, acc[i][3]);
                        acc[i][0] = fmaf(a.z, w2.x, acc[i][0]);
                        acc[i][1] = fmaf(a.z, w2.y, acc[i][1]);
                        acc[i][2] = fmaf(a.z, w2.z, acc[i][2]);
                        acc[i][3] = fmaf(a.z, w2.w, acc[i][3]);
                        acc[i][0] = fmaf(a.w, w3.x, acc[i][0]);
                        acc[i][1] = fmaf(a.w, w3.y, acc[i][1]);
                        acc[i][2] = fmaf(a.w, w3.z, acc[i][2]);
                        acc[i][3] = fmaf(a.w, w3.w, acc[i][3]);
                    }
                }
            }
            {   // h-part: k in [ks*128, ks*128+128)
                const float* pkh = pk + (size_t)(NIN + ks * 128) * 16;
                const float* hp  = hcur + (size_t)ks * 128;
#pragma unroll 2
                for (int q = 0; q < 32; ++q) {
                    const int k4 = q * 4;
                    const float4 w0 = *(const float4*)(pkh + (k4 + 0) * 16);
                    const float4 w1 = *(const float4*)(pkh + (k4 + 1) * 16);
                    const float4 w2 = *(const float4*)(pkh + (k4 + 2) * 16);
                    const float4 w3 = *(const float4*)(pkh + (k4 + 3) * 16);
#pragma unroll
                    for (int i = 0; i < 4; ++i) {
                        const float4 a = *(const float4*)(hp +
                            (size_t)(r0 + i) * NH + k4);
                        acc[i][0] = fmaf(a.x, w0.x, acc[i][0]);
                        acc[i][1] = fmaf(a.x, w0.y, acc[i][1]);
                        acc[i][2] = fmaf(a.x, w0.z, acc[i][2]);
                        acc[i][3] = fmaf(a.x, w0.w, acc[i][3]);
                        acc[i][0] = fmaf(a.y, w1.x, acc[i][0]);
                        acc[i][1] = fmaf(a.y, w1.y, acc[i][1]);
                        acc[i][2] = fmaf(a.y, w1.z, acc[i][2]);
                        acc[i][3] = fmaf(a.y, w1.w, acc[i][3]);
                        acc[i][0] = fmaf(a.z, w2.x, acc[i][0]);
                        acc[i][1] = fmaf(a.z, w2.y, acc[i][1]);
                        acc[i][2] = fmaf(a.z, w2.z, acc[i][2]);
                        acc[i][3] = fmaf(a.z, w2.w, acc[i][3]);
                        acc[i][0] = fmaf(a.w, w3.x, acc[i][0]);
                        acc[i][1] = fmaf(a.w, w3.y, acc[i][1]);
                        acc[i][2] = fmaf(a.w, w3.z, acc[i][2]);
                        acc[i][3] = fmaf(a.w, w3.w, acc[i][3]);
                    }
                }
            }
        } else {
            const float* Wu = A.Wu[cgi] + c0;
            const float* Wh = A.Wh[cgi] + c0;
            {   // u-part
                const int kb = ks * 64;
#pragma unroll 2
                for (int q = 0; q < 16; ++q) {
                    const int k = kb + q * 4;
                    const float4 w0 = *(const float4*)(Wu + (size_t)(k + 0) * NH);
                    const float4 w1 = *(const float4*)(Wu + (size_t)(k + 1) * NH);
                    const float4 w2 = *(const float4*)(Wu + (size_t)(k + 2) * NH);
                    const float4 w3 = *(const float4*)(Wu + (size_t)(k + 3) * NH);
#pragma unroll
                    for (int i = 0; i < 4; ++i) {
                        const float4 a = *(const float4*)(A.u +
                            ((size_t)(r0 + i) * TDIM + t) * NIN + k);
                        acc[i][0] = fmaf(a.x, w0.x, acc[i][0]);
                        acc[i][1] = fmaf(a.x, w0.y, acc[i][1]);
                        acc[i][2] = fmaf(a.x, w0.z, acc[i][2]);
                        acc[i][3] = fmaf(a.x, w0.w, acc[i][3]);
                        acc[i][0] = fmaf(a.y, w1.x, acc[i][0]);
                        acc[i][1] = fmaf(a.y, w1.y, acc[i][1]);
                        acc[i][2] = fmaf(a.y, w1.z, acc[i][2]);
                        acc[i][3] = fmaf(a.y, w1.w, acc[i][3]);
                        acc[i][0] = fmaf(a.z, w2.x, acc[i][0]);
                        acc[i][1] = fmaf(a.z, w2.y, acc[i][1]);
                        acc[i][2] = fmaf(a.z, w2.z, acc[i][2]);
                        acc[i][3] = fmaf(a.z, w2.w, acc[i][3]);
                        acc[i][0] = fmaf(a.w, w3.x, acc[i][0]);
                        acc[i][1] = fmaf(a.w, w3.y, acc[i][1]);
                        acc[i][2] = fmaf(a.w, w3.z, acc[i][2]);
                        acc[i][3] = fmaf(a.w, w3.w, acc[i][3]);
                    }
                }
            }
            {   // h-part
                const int kb = ks * 128;
#pragma unroll 2
                for (int q = 0; q < 32; ++q) {
                    const int k = kb + q * 4;
                    const float4 w0 = *(const float4*)(Wh + (size_t)(k + 0) * NH);
                    const float4 w1 = *(const float4*)(Wh + (size_t)(k + 1) * NH);
                    const float4 w2 = *(const float4*)(Wh + (size_t)(k + 2) * NH);
                    const float4 w3 = *(const float4*)(Wh + (size_t)(k + 3) * NH);
#pragma unroll
                    for (int i = 0; i < 4; ++i) {
                        const float4 a = *(const float4*)(hcur +
                            (size_t)(r0 + i) * NH + k);
                        acc[i][0] = fmaf(a.x, w0.x, acc[i][0]);
                        acc[i][1] = fmaf(a.x, w0.y, acc[i][1]);
                        acc[i][2] = fmaf(a.x, w0.z, acc[i][2]);
                        acc[i][3] = fmaf(a.x, w0.w, acc[i][3]);
                        acc[i][0] = fmaf(a.y, w1.x, acc[i][0]);
                        acc[i][1] = fmaf(a.y, w1.y, acc[i][1]);
                        acc[i][2] = fmaf(a.y, w1.z, acc[i][2]);
                        acc[i][3] = fmaf(a.y, w1.w, acc[i][3]);
                        acc[i][0] = fmaf(a.z, w2.x, acc[i][0]);
                        acc[i][1] = fmaf(a.z, w2.y, acc[i][1]);
                        acc[i][2] = fmaf(a.z, w2.z, acc[i][2]);
                        acc[i][3] = fmaf(a.z, w2.w, acc[i][3]);
                        acc[i][0] = fmaf(a.w, w3.x, acc[i][0]);
                        acc[i][1] = fmaf(a.w, w3.y, acc[i][1]);
                        acc[i][2] = fmaf(a.w, w3.z, acc[i][2]);
                        acc[i][3] = fmaf(a.w, w3.w, acc[i][3]);
                    }
                }
            }
        }
        // reduce over ks (lane bits 0..2) via in-wave butterfly
#pragma unroll
        for (int i = 0; i < 4; ++i)
#pragma unroll
            for (int j = 0; j < 4; ++j) {
                float v = acc[i][j];
                v += __shfl_xor(v, 1);
                v += __shfl_xor(v, 2);
                v += __shfl_xor(v, 4);
                acc[i][j] = v;
            }
        if (ks == 0) {
#pragma unroll
            for (int i = 0; i < 4; ++i)
                *(float4*)&pre[(size_t)(r0 + i) * 20 + cgi * 4] =
                    make_float4(acc[i][0], acc[i][1], acc[i][2], acc[i][3]);
        }
    }

    // ------------- Y logits (y_{it-1} from h_it), blocks 0..127 -------------
    if (it >= 1 && it <= TDIM && bx < 128) {
        const int r  = (bx & 1) * 64 + (tid >> 4);
        const int c  = ((bx >> 1) << 2) + ((tid >> 2) & 3);
        const int kb = (tid & 3) * 256;
        const float* hp = hcur + (size_t)r * NH + kb;
        const float* wp = A.WhyT + (size_t)c * NH + kb;
        float ya = 0.f;
#pragma unroll 4
        for (int q = 0; q < 64; ++q) {
            const float4 h4 = *(const float4*)(hp + q * 4);
            const float4 w4 = *(const float4*)(wp + q * 4);
            ya = fmaf(h4.x, w4.x, ya);
            ya = fmaf(h4.y, w4.y, ya);
            ya = fmaf(h4.z, w4.z, ya);
            ya = fmaf(h4.w, w4.w, ya);
        }
        ya += __shfl_xor(ya, 1);
        ya += __shfl_xor(ya, 2);
        if ((tid & 3) == 0) Lw[(size_t)r * NOUT + c] = ya + A.by[c];
    }

    __syncthreads();

    // ---------------- gate combine -> h_{it+1} ----------------
    if (it < TDIM && tid < 512) {
        const int row = tid >> 2, hc = tid & 3;
        const float* pr = pre + (size_t)row * 20 + hc;
        const float gf = sigmoidf_(pr[0]  + A.bg[0][c0 + hc]);
        const float gi = sigmoidf_(pr[4]  + A.bg[1][c0 + hc]);
        const float go = sigmoidf_(pr[8]  + A.bg[2][c0 + hc]);
        const float ct = tanhf    (pr[12] + A.bg[3][c0 + hc]);
        const float ho = hcur[(size_t)row * NH + c0 + hc];
        // faithful to source: c_new = f*h + i*c_tilde  (uses h, not c)
        const float cn = gf * ho + gi * ct;
        hnext[(size_t)row * NH + c0 + hc] = go * tanhf(cn);
    }
}

template <bool PACKED>
__global__ __launch_bounds__(1024, 4) void scan_coop(ScanArgs A)
{
    __shared__ float pre[BDIM * 20];
    cg::grid_group grid = cg::this_grid();
    for (int it = 0; it < NITER; ++it) {
        scan_iter<PACKED>(A, it, pre);
        grid.sync();
    }
}

template <bool PACKED>
__global__ __launch_bounds__(1024, 4) void scan_step(ScanArgs A, int it)
{
    __shared__ float pre[BDIM * 20];
    scan_iter<PACKED>(A, it, pre);
}

// ---------------------------------------------------------------------------
// One-time packing: Wpack[cc][k][g*4+j] = (k<512 ? Wu_g : Wh_g)[k'][cc*4+j]
// ---------------------------------------------------------------------------
__global__ void pack_weights(
    const float* __restrict__ Wuf, const float* __restrict__ Wui,
    const float* __restrict__ Wuo, const float* __restrict__ Wuc,
    const float* __restrict__ Whf, const float* __restrict__ Whi,
    const float* __restrict__ Who, const float* __restrict__ Whc,
    float* __restrict__ Wpack)
{
    const int cc = blockIdx.x;
    const int c0 = cc * 4;
    const float* Wu[4] = {Wuf, Wui, Wuo, Wuc};
    const float* Wh[4] = {Whf, Whi, Who, Whc};
    for (int k = threadIdx.x; k < KTOT; k += 256) {
        float4* dst = (float4*)(Wpack + ((size_t)cc * KTOT + k) * 16);
#pragma unroll
        for (int g = 0; g < 4; ++g) {
            const float* src = (k < NIN)
                ? (Wu[g] + (size_t)k * NH + c0)
                : (Wh[g] + (size_t)(k - NIN) * NH + c0);
            dst[g] = *(const float4*)src;
        }
    }
}

__global__ void transpose_why(const float* __restrict__ Why,
                              float* __restrict__ WhyT)
{
    __shared__ float tile[32][33];
    const int k0 = blockIdx.x * 32;
    const int n0 = blockIdx.y * 32;
    const int tx = threadIdx.x, ty = threadIdx.y;
#pragma unroll
    for (int r = 0; r < 4; ++r)
        tile[ty * 4 + r][tx] = Why[(size_t)(k0 + ty * 4 + r) * NOUT + n0 + tx];
    __syncthreads();
#pragma unroll
    for (int r = 0; r < 4; ++r)
        WhyT[(size_t)(n0 + ty * 4 + r) * NH + k0 + tx] = tile[tx][ty * 4 + r];
}

__global__ void init_h(const float* __restrict__ h0, float* __restrict__ hb)
{
    const int i = blockIdx.x * 256 + threadIdx.x;
    hb[i] = h0[i & (NH - 1)];
}

// ---------------------------------------------------------------------------
extern "C" void kernel_launch(void* const* d_in, const int* in_sizes, int n_in,
                              void* d_out, int out_size, void* d_ws, size_t ws_size,
                              hipStream_t stream)
{
    (void)in_sizes; (void)n_in; (void)out_size;
    const float* u   = (const float*)d_in[0];
    const float* Wuf = (const float*)d_in[1];
    const float* Wui = (const float*)d_in[2];
    const float* Wuo = (const float*)d_in[3];
    const float* Wuc = (const float*)d_in[4];
    const float* Whf = (const float*)d_in[5];
    const float* Whi = (const float*)d_in[6];
    const float* Who = (const float*)d_in[7];
    const float* Whc = (const float*)d_in[8];
    const float* Why = (const float*)d_in[9];
    const float* bf  = (const float*)d_in[10];
    const float* bi  = (const float*)d_in[11];
    const float* bo  = (const float*)d_in[12];
    const float* bc  = (const float*)d_in[13];
    const float* by  = (const float*)d_in[14];
    const float* h0  = (const float*)d_in[15];
    float* out = (float*)d_out;

    // workspace layout: small buffers first, pack last (optional)
    float* WhyT = (float*)d_ws;                       // 256*1024  = 1 MB
    float* hb0  = WhyT + (size_t)NOUT * NH;           // 128*1024
    float* hb1  = hb0  + (size_t)BDIM * NH;
    float* lg0  = hb1  + (size_t)BDIM * NH;           // 128*256
    float* lg1  = lg0  + (size_t)BDIM * NOUT;
    float* Wpk  = lg1  + (size_t)BDIM * NOUT;         // 256*1536*16 = 24 MB

    const size_t smallElems = (size_t)NOUT * NH + 2 * (size_t)BDIM * NH
                            + 2 * (size_t)BDIM * NOUT;
    const size_t packElems  = (size_t)256 * KTOT * 16;
    const bool usePack = ws_size >= (smallElems + packElems) * sizeof(float);

    transpose_why<<<dim3(NH / 32, NOUT / 32), dim3(32, 8), 0, stream>>>(Why, WhyT);
    init_h<<<dim3(BDIM * NH / 256), dim3(256), 0, stream>>>(h0, hb0);
    if (usePack)
        pack_weights<<<dim3(256), dim3(256), 0, stream>>>(
            Wuf, Wui, Wuo, Wuc, Whf, Whi, Who, Whc, Wpk);

    ScanArgs A;
    A.u = u;
    A.Wu[0] = Wuf; A.Wu[1] = Wui; A.Wu[2] = Wuo; A.Wu[3] = Wuc;
    A.Wh[0] = Whf; A.Wh[1] = Whi; A.Wh[2] = Who; A.Wh[3] = Whc;
    A.Wpack = Wpk; A.WhyT = WhyT;
    A.bg[0] = bf; A.bg[1] = bi; A.bg[2] = bo; A.bg[3] = bc;
    A.by = by;
    A.hb0 = hb0; A.hb1 = hb1; A.lg0 = lg0; A.lg1 = lg1;
    A.out = out;

    void* args[] = { (void*)&A };
    hipError_t e;
    if (usePack)
        e = hipLaunchCooperativeKernel((void*)scan_coop<true>, dim3(256),
                                       dim3(1024), args, 0, stream);
    else
        e = hipLaunchCooperativeKernel((void*)scan_coop<false>, dim3(256),
                                       dim3(1024), args, 0, stream);
    if (e != hipSuccess) {
        // fallback: per-iteration launches; kernel boundary provides the sync
        for (int it = 0; it < NITER; ++it) {
            if (usePack)
                scan_step<true><<<dim3(256), dim3(1024), 0, stream>>>(A, it);
            else
                scan_step<false><<<dim3(256), dim3(1024), 0, stream>>>(A, it);
        }
    }
}